// Round 7
// baseline (401.777 us; speedup 1.0000x reference)
//
#include <hip/hip_runtime.h>
#include <cstdint>
#include <cstddef>

// DigitCapsule dynamic routing, fp32. b-per-lane, j-loop-inside, W in LDS,
// atomic s-reduction. x[256,1152,8], W[1152,10,16,8], out v[256,10,16].
// vsum trick: logits at round r = votes . (v0+...+v_{r-1}).
constexpr int Bn = 256, In = 1152, Pn = 8, Jn = 10, Dn = 16;
constexpr int CA = 2, NCH = In / CA;  // 576 blocks for capsA/capsB

// One-time transpose x[B][I*P] -> xT[I*P][B] (lane=b coalescing) + zero s_acc.
__global__ __launch_bounds__(256) void xpose_init(const float* __restrict__ x,
                                                  float* __restrict__ xT,
                                                  float* __restrict__ s_acc) {
  __shared__ float tile[64][65];
  const int t = threadIdx.x, r = t >> 6, c = t & 63;
  const int ip0 = blockIdx.x * 64, b0 = blockIdx.y * 64;
  const size_t gid = ((size_t)blockIdx.y * gridDim.x + blockIdx.x) * 256 + t;
  if (gid < (size_t)Jn * Dn * Bn) s_acc[gid] = 0.f;  // 576 blocks cover 40960
  #pragma unroll
  for (int k = 0; k < 16; ++k) {
    const int row = k * 4 + r;
    tile[row][c] = x[(size_t)(b0 + row) * (In * Pn) + ip0 + c];
  }
  __syncthreads();
  #pragma unroll
  for (int k = 0; k < 16; ++k) {
    const int row = k * 4 + r;
    xT[(size_t)(ip0 + row) * Bn + b0 + c] = tile[c][row];
  }
}

// capsA: for its 2 i's, loop ALL j: acc[d] = sum_i c*vote(b,i,j,d), atomic into
// s_acc. x and c hoisted to registers; W LDS-broadcast. ~2880 FMA / 40 loads.
// MODE 0: c = 1 (0.1 folded into capsF) ; MODE 1: c from cbuf[j][i][b].
template <int MODE>
__global__ __launch_bounds__(256) void capsA(
    const float* __restrict__ xT, const float* __restrict__ w,
    const float* __restrict__ cbuf, float* __restrict__ s_acc) {
  __shared__ alignas(16) float wlds[CA * 1280];  // 10 KB
  const int t = threadIdx.x, b = t;
  const int i0 = blockIdx.x * CA;

  {  // stage W[i0..i0+1][*][*][*]: 2560 dwords = 640 float4, coalesced
    const float4* wsrc = (const float4*)(w + (size_t)i0 * (Jn * Dn * Pn));
    float4* wdst = (float4*)wlds;
    #pragma unroll
    for (int k = 0; k < 3; ++k) {
      const int e = t + k * 256;
      if (e < CA * 320) wdst[e] = wsrc[e];
    }
  }
  __syncthreads();

  float xv[CA][Pn];
  #pragma unroll
  for (int ii = 0; ii < CA; ++ii) {
    const float* xr = xT + (size_t)(i0 + ii) * (Pn * Bn) + b;
    #pragma unroll
    for (int p = 0; p < Pn; ++p) xv[ii][p] = xr[p * Bn];
  }
  float cv[Jn][CA];
  if (MODE == 1) {
    #pragma unroll
    for (int j = 0; j < Jn; ++j)
      #pragma unroll
      for (int ii = 0; ii < CA; ++ii)
        cv[j][ii] = cbuf[((size_t)j * In + i0 + ii) * Bn + b];
  }

  #pragma unroll 1
  for (int j = 0; j < Jn; ++j) {
    float acc[Dn];
    #pragma unroll
    for (int d = 0; d < Dn; ++d) acc[d] = 0.f;
    #pragma unroll
    for (int ii = 0; ii < CA; ++ii) {
      float xc[Pn];
      #pragma unroll
      for (int p = 0; p < Pn; ++p)
        xc[p] = (MODE == 0) ? xv[ii][p] : xv[ii][p] * cv[j][ii];
      const float4* wf = (const float4*)&wlds[ii * 1280 + j * 128];
      #pragma unroll
      for (int d = 0; d < Dn; ++d) {
        const float4 w0 = wf[d * 2];      // ds_read_b128 broadcast
        const float4 w1 = wf[d * 2 + 1];
        float dot = w0.x * xc[0];
        dot = fmaf(w0.y, xc[1], dot); dot = fmaf(w0.z, xc[2], dot);
        dot = fmaf(w0.w, xc[3], dot); dot = fmaf(w1.x, xc[4], dot);
        dot = fmaf(w1.y, xc[5], dot); dot = fmaf(w1.z, xc[6], dot);
        dot = fmaf(w1.w, xc[7], dot);
        acc[d] += dot;
      }
    }
    #pragma unroll
    for (int d = 0; d < Dn; ++d)
      atomicAdd(&s_acc[((size_t)j * Dn + d) * Bn + b], acc[d]);
  }
}

// capsF: squash s_acc, update vsumT, rezero s_acc. Grid (j=10, bgroup=4) x 64.
// MODE 0: vsum = squash(0.1*s) ; MODE 1: vsum += squash(s) ; MODE 2: out.
template <int MODE>
__global__ __launch_bounds__(64) void capsF(float* __restrict__ s_acc,
                                            float* __restrict__ vsumT,
                                            float* __restrict__ out) {
  const int j = blockIdx.x, b = blockIdx.y * 64 + threadIdx.x;
  float sv[Dn], n2 = 0.f;
  #pragma unroll
  for (int d = 0; d < Dn; ++d) {
    float z = s_acc[((size_t)j * Dn + d) * Bn + b];
    if (MODE == 0) z *= 0.1f;  // uniform c folded here
    sv[d] = z;
    n2 = fmaf(z, z, n2);
  }
  const float sc = n2 / (1.f + n2) / sqrtf(n2 + 1e-7f);
  #pragma unroll
  for (int d = 0; d < Dn; ++d) {
    const size_t o = ((size_t)j * Dn + d) * Bn + b;
    if (MODE == 2) {
      out[((size_t)b * Jn + j) * Dn + d] = sv[d] * sc;
    } else {
      if (MODE == 0) vsumT[o] = sv[d] * sc;
      else           vsumT[o] += sv[d] * sc;
      s_acc[o] = 0.f;  // ready for next round's atomics
    }
  }
}

// capsB: l[j] = votes(b,i,j,:).vsum[b,j,:]; c = softmax_j -> cbuf[j][i][b].
// thread=b, block = 2 i's. x hoisted; W LDS-broadcast; vsum re-read per j
// (16 loads per ~600-cyc j-iter, covered by multi-wave overlap).
__global__ __launch_bounds__(256) void capsB(
    const float* __restrict__ xT, const float* __restrict__ w,
    const float* __restrict__ vsumT, float* __restrict__ cbuf) {
  __shared__ alignas(16) float wlds[CA * 1280];  // 10 KB
  const int t = threadIdx.x, b = t;
  const int i0 = blockIdx.x * CA;

  {
    const float4* wsrc = (const float4*)(w + (size_t)i0 * (Jn * Dn * Pn));
    float4* wdst = (float4*)wlds;
    #pragma unroll
    for (int k = 0; k < 3; ++k) {
      const int e = t + k * 256;
      if (e < CA * 320) wdst[e] = wsrc[e];
    }
  }
  __syncthreads();

  float xv[CA][Pn];
  #pragma unroll
  for (int ii = 0; ii < CA; ++ii) {
    const float* xr = xT + (size_t)(i0 + ii) * (Pn * Bn) + b;
    #pragma unroll
    for (int p = 0; p < Pn; ++p) xv[ii][p] = xr[p * Bn];
  }

  float l[CA][Jn];
  #pragma unroll 1
  for (int j = 0; j < Jn; ++j) {
    #pragma unroll
    for (int ii = 0; ii < CA; ++ii) {
      const float4* wf = (const float4*)&wlds[ii * 1280 + j * 128];
      float acc = 0.f;
      #pragma unroll
      for (int d = 0; d < Dn; ++d) {
        const float4 w0 = wf[d * 2];
        const float4 w1 = wf[d * 2 + 1];
        float dot = w0.x * xv[ii][0];
        dot = fmaf(w0.y, xv[ii][1], dot); dot = fmaf(w0.z, xv[ii][2], dot);
        dot = fmaf(w0.w, xv[ii][3], dot); dot = fmaf(w1.x, xv[ii][4], dot);
        dot = fmaf(w1.y, xv[ii][5], dot); dot = fmaf(w1.z, xv[ii][6], dot);
        dot = fmaf(w1.w, xv[ii][7], dot);
        acc = fmaf(dot, vsumT[((size_t)j * Dn + d) * Bn + b], acc);
      }
      l[ii][j] = acc;
    }
  }

  #pragma unroll
  for (int ii = 0; ii < CA; ++ii) {
    float m = l[ii][0];
    #pragma unroll
    for (int j = 1; j < Jn; ++j) m = fmaxf(m, l[ii][j]);
    float ssum = 0.f;
    #pragma unroll
    for (int j = 0; j < Jn; ++j) { l[ii][j] = __expf(l[ii][j] - m); ssum += l[ii][j]; }
    const float inv = 1.f / ssum;
    #pragma unroll
    for (int j = 0; j < Jn; ++j)
      cbuf[((size_t)j * In + (i0 + ii)) * Bn + b] = l[ii][j] * inv;
  }
}

extern "C" void kernel_launch(void* const* d_in, const int* in_sizes, int n_in,
                              void* d_out, int out_size, void* d_ws, size_t ws_size,
                              hipStream_t stream) {
  const float* x = (const float*)d_in[0];  // [256,1152,8]
  const float* w = (const float*)d_in[1];  // [1152,10,16,8]
  float* xT    = (float*)d_ws;                  // [I*P][B]  9.44 MB
  float* s_acc = xT + (size_t)In * Pn * Bn;     // [J][D][B] 160 KB
  float* vsumT = s_acc + (size_t)Jn * Dn * Bn;  // [J][D][B] 160 KB
  float* cbuf  = vsumT + (size_t)Jn * Dn * Bn;  // [J][I][B] 11.8 MB
  float* out = (float*)d_out;                   // [256,10,16]

  dim3 gX((In * Pn) / 64, Bn / 64);  // 144 x 4
  dim3 gF(Jn, Bn / 64);              // 10 x 4

  xpose_init<<<gX, 256, 0, stream>>>(x, xT, s_acc);

  capsA<0><<<NCH, 256, 0, stream>>>(xT, w, nullptr, s_acc);  // sum votes
  capsF<0><<<gF, 64, 0, stream>>>(s_acc, vsumT, nullptr);    // v0 (0.1 folded)

  capsB<<<NCH, 256, 0, stream>>>(xT, w, vsumT, cbuf);        // c1
  capsA<1><<<NCH, 256, 0, stream>>>(xT, w, cbuf, s_acc);
  capsF<1><<<gF, 64, 0, stream>>>(s_acc, vsumT, nullptr);    // vsum += v1

  capsB<<<NCH, 256, 0, stream>>>(xT, w, vsumT, cbuf);        // c2
  capsA<1><<<NCH, 256, 0, stream>>>(xT, w, cbuf, s_acc);
  capsF<2><<<gF, 64, 0, stream>>>(s_acc, vsumT, out);        // out = v2
}

// Round 8
// 398.719 us; speedup vs baseline: 1.0077x; 1.0077x over previous
//
#include <hip/hip_runtime.h>
#include <cstdint>
#include <cstddef>

// DigitCapsule dynamic routing, fp32. 4-b-per-lane, j-in-grid, wave-uniform W
// (VMEM/SMEM broadcast, no LDS), plain spart stores (no atomics).
// x[256,1152,8], W[1152,10,16,8], out v[256,10,16].
// vsum trick: logits at round r = votes . (v0+...+v_{r-1}).
constexpr int Bn = 256, In = 1152, Pn = 8, Jn = 10, Dn = 16;
constexpr int CA = 12, NCH = In / CA;  // 96 chunks; grid (96,10) keeps a
                                       // chunk's 10 j-blocks on one XCD (96%8==0)

// One-time transpose x[B][I*P] -> xT[I*P][B] so lane-quad b-reads coalesce.
__global__ __launch_bounds__(256) void xpose(const float* __restrict__ x,
                                             float* __restrict__ xT) {
  __shared__ float tile[64][65];
  const int t = threadIdx.x, r = t >> 6, c = t & 63;
  const int ip0 = blockIdx.x * 64, b0 = blockIdx.y * 64;
  #pragma unroll
  for (int k = 0; k < 16; ++k) {
    const int row = k * 4 + r;
    tile[row][c] = x[(size_t)(b0 + row) * (In * Pn) + ip0 + c];
  }
  __syncthreads();
  #pragma unroll
  for (int k = 0; k < 16; ++k) {
    const int row = k * 4 + r;
    xT[(size_t)(ip0 + row) * Bn + b0 + c] = tile[c][row];
  }
}

// capsA: spart[ch][j][d][b] = sum_{i in chunk} c[b,i,j]*vote(b,i,j,d).
// Lane l owns b=4l..4l+3 (float4 components). Wave wv owns d in [4wv,4wv+4).
// W loads wave-uniform. MODE 0: c=1 (0.1 folded into capsF). MODE 1: c=cbuf.
template <int MODE>
__global__ __launch_bounds__(256, 4) void capsA(
    const float* __restrict__ xT, const float* __restrict__ w,
    const float* __restrict__ cbuf, float* __restrict__ spart) {
  const int t = threadIdx.x, wv = t >> 6, l = t & 63;
  const int ch = blockIdx.x, j = blockIdx.y;
  const int i0 = ch * CA;

  float4 acc[4];
  #pragma unroll
  for (int dd = 0; dd < 4; ++dd) acc[dd] = make_float4(0.f, 0.f, 0.f, 0.f);

  for (int ii = 0; ii < CA; ++ii) {
    const int i = i0 + ii;
    // x for this lane's b-quad: one float4 per p (coalesced, 1KB/wave-instr)
    float4 xc[Pn];
    const float* xb = xT + (size_t)i * (Pn * Bn) + 4 * l;
    #pragma unroll
    for (int p = 0; p < Pn; ++p) xc[p] = *(const float4*)(xb + p * Bn);
    if (MODE == 1) {
      const float4 cq = *(const float4*)(cbuf + ((size_t)j * In + i) * Bn + 4 * l);
      #pragma unroll
      for (int p = 0; p < Pn; ++p) {
        xc[p].x *= cq.x; xc[p].y *= cq.y; xc[p].z *= cq.z; xc[p].w *= cq.w;
      }
    }
    // W for this wave's 4 d's: 32 wave-uniform scalars
    const float* wr = w + ((size_t)i * Jn + j) * (Dn * Pn) + wv * 4 * Pn;
    #pragma unroll
    for (int dd = 0; dd < 4; ++dd) {
      #pragma unroll
      for (int p = 0; p < Pn; ++p) {
        const float ws = wr[dd * Pn + p];
        acc[dd].x = fmaf(ws, xc[p].x, acc[dd].x);
        acc[dd].y = fmaf(ws, xc[p].y, acc[dd].y);
        acc[dd].z = fmaf(ws, xc[p].z, acc[dd].z);
        acc[dd].w = fmaf(ws, xc[p].w, acc[dd].w);
      }
    }
  }
  #pragma unroll
  for (int dd = 0; dd < 4; ++dd) {
    const int d = wv * 4 + dd;
    *(float4*)(spart + (((size_t)ch * Jn + j) * Dn + d) * Bn + 4 * l) = acc[dd];
  }
}

// capsF: reduce spart over 96 chunks, squash. Grid (j=10, bgroup=4) x 256.
// MODE 0: vsum = squash(0.1*s) ; MODE 1: vsum += squash(s) ; MODE 2: out.
template <int MODE>
__global__ __launch_bounds__(256) void capsF(const float* __restrict__ spart,
                                             float* __restrict__ vsumT,
                                             float* __restrict__ out) {
  __shared__ float red[4][64][17];
  const int t = threadIdx.x, bl = t & 63, cg = t >> 6;
  const int j = blockIdx.x, b = blockIdx.y * 64 + bl;
  float s[Dn];
  #pragma unroll
  for (int d = 0; d < Dn; ++d) s[d] = 0.f;
  for (int ch = cg; ch < NCH; ch += 4) {
    const float* sp = spart + ((size_t)ch * Jn + j) * (Dn * Bn) + b;
    #pragma unroll
    for (int d = 0; d < Dn; ++d) s[d] += sp[(size_t)d * Bn];
  }
  #pragma unroll
  for (int d = 0; d < Dn; ++d) red[cg][bl][d] = s[d];
  __syncthreads();
  if (t < 64) {
    float v[Dn], n2 = 0.f;
    #pragma unroll
    for (int d = 0; d < Dn; ++d) {
      float z = red[0][bl][d] + red[1][bl][d] + red[2][bl][d] + red[3][bl][d];
      if (MODE == 0) z *= 0.1f;  // uniform c folded here
      v[d] = z;
      n2 = fmaf(z, z, n2);
    }
    const float sc = n2 / (1.f + n2) / sqrtf(n2 + 1e-7f);
    #pragma unroll
    for (int d = 0; d < Dn; ++d) {
      const size_t o = ((size_t)j * Dn + d) * Bn + b;
      if (MODE == 2)      out[((size_t)b * Jn + j) * Dn + d] = v[d] * sc;
      else if (MODE == 0) vsumT[o] = v[d] * sc;
      else                vsumT[o] += v[d] * sc;
    }
  }
}

// capsB: lbuf[j][i][b] = votes(b,i,j,:).vsum[b,j,:]. Lane owns b-quad; the 4
// waves split the chunk's i's; vsum hoisted per block (j fixed). No LDS.
__global__ __launch_bounds__(256, 4) void capsB(
    const float* __restrict__ xT, const float* __restrict__ w,
    const float* __restrict__ vsumT, float* __restrict__ lbuf) {
  const int t = threadIdx.x, wv = t >> 6, l = t & 63;
  const int ch = blockIdx.x, j = blockIdx.y;

  float4 vs[Dn];  // this lane's b-quad slice of vsum[b,j,:]
  #pragma unroll
  for (int d = 0; d < Dn; ++d)
    vs[d] = *(const float4*)(vsumT + ((size_t)j * Dn + d) * Bn + 4 * l);

  const int nper = CA / 4;  // i's per wave
  for (int k = 0; k < nper; ++k) {
    const int i = ch * CA + wv * nper + k;
    float4 xp[Pn];
    const float* xb = xT + (size_t)i * (Pn * Bn) + 4 * l;
    #pragma unroll
    for (int p = 0; p < Pn; ++p) xp[p] = *(const float4*)(xb + p * Bn);

    const float* wr = w + ((size_t)i * Jn + j) * (Dn * Pn);
    float4 lac = make_float4(0.f, 0.f, 0.f, 0.f);
    #pragma unroll
    for (int d = 0; d < Dn; ++d) {
      float4 vt = make_float4(0.f, 0.f, 0.f, 0.f);
      #pragma unroll
      for (int p = 0; p < Pn; ++p) {
        const float ws = wr[d * Pn + p];
        vt.x = fmaf(ws, xp[p].x, vt.x);
        vt.y = fmaf(ws, xp[p].y, vt.y);
        vt.z = fmaf(ws, xp[p].z, vt.z);
        vt.w = fmaf(ws, xp[p].w, vt.w);
      }
      lac.x = fmaf(vt.x, vs[d].x, lac.x);
      lac.y = fmaf(vt.y, vs[d].y, lac.y);
      lac.z = fmaf(vt.z, vs[d].z, lac.z);
      lac.w = fmaf(vt.w, vs[d].w, lac.w);
    }
    *(float4*)(lbuf + ((size_t)j * In + i) * Bn + 4 * l) = lac;
  }
}

// smax: c[j][i][b] = softmax_j(lbuf[j][i][b]). Thread = one (b,i).
__global__ __launch_bounds__(256) void smax(const float* __restrict__ lbuf,
                                            float* __restrict__ cbuf) {
  const size_t tid = (size_t)blockIdx.x * 256 + threadIdx.x;
  const int b = (int)(tid & (Bn - 1));
  const int i = (int)(tid >> 8);
  float lv[Jn];
  #pragma unroll
  for (int j = 0; j < Jn; ++j) lv[j] = lbuf[((size_t)j * In + i) * Bn + b];
  float m = lv[0];
  #pragma unroll
  for (int j = 1; j < Jn; ++j) m = fmaxf(m, lv[j]);
  float ssum = 0.f;
  #pragma unroll
  for (int j = 0; j < Jn; ++j) { lv[j] = __expf(lv[j] - m); ssum += lv[j]; }
  const float inv = 1.f / ssum;
  #pragma unroll
  for (int j = 0; j < Jn; ++j)
    cbuf[((size_t)j * In + i) * Bn + b] = lv[j] * inv;
}

extern "C" void kernel_launch(void* const* d_in, const int* in_sizes, int n_in,
                              void* d_out, int out_size, void* d_ws, size_t ws_size,
                              hipStream_t stream) {
  const float* x = (const float*)d_in[0];  // [256,1152,8]
  const float* w = (const float*)d_in[1];  // [1152,10,16,8]
  float* xT    = (float*)d_ws;                   // [I*P][B]        9.44 MB
  float* spart = xT + (size_t)In * Pn * Bn;      // [NCH][J][D][B] 15.73 MB
  float* vsumT = spart + (size_t)NCH * Jn * Dn * Bn;  // [J][D][B]  160 KB
  float* lbuf  = vsumT + (size_t)Jn * Dn * Bn;   // [J][I][B]      11.8 MB
  float* cbuf  = lbuf + (size_t)Jn * In * Bn;    // [J][I][B]      11.8 MB
  float* out = (float*)d_out;                    // [256,10,16]

  dim3 gX((In * Pn) / 64, Bn / 64);  // 144 x 4
  dim3 gAB(NCH, Jn);                 // 96 x 10 (ch fast => chunk stays on XCD)
  dim3 gF(Jn, Bn / 64);              // 10 x 4
  const int gS = (Bn * In) / 256;    // 1152 blocks

  xpose<<<gX, 256, 0, stream>>>(x, xT);

  capsA<0><<<gAB, 256, 0, stream>>>(xT, w, nullptr, spart);
  capsF<0><<<gF, 256, 0, stream>>>(spart, vsumT, nullptr);   // v0 (0.1 folded)

  capsB<<<gAB, 256, 0, stream>>>(xT, w, vsumT, lbuf);        // logits r1
  smax<<<gS, 256, 0, stream>>>(lbuf, cbuf);                  // c1
  capsA<1><<<gAB, 256, 0, stream>>>(xT, w, cbuf, spart);
  capsF<1><<<gF, 256, 0, stream>>>(spart, vsumT, nullptr);   // vsum += v1

  capsB<<<gAB, 256, 0, stream>>>(xT, w, vsumT, lbuf);        // logits r2
  smax<<<gS, 256, 0, stream>>>(lbuf, cbuf);                  // c2
  capsA<1><<<gAB, 256, 0, stream>>>(xT, w, cbuf, spart);
  capsF<2><<<gF, 256, 0, stream>>>(spart, vsumT, out);       // out = v2
}